// Round 6
// baseline (355.253 us; speedup 1.0000x reference)
//
#include <hip/hip_runtime.h>
#include <math.h>

#define NH 8
#define DH 80
#define NTOK 2048
#define QD 640
#define SCALE_F 0.11180339887498949f
#define TSCALE_F (1.2f * SCALE_F)
#define GAMMA_F 0.3f
#define LMAX_F 2.5f
#define TOPKN 128

typedef __attribute__((ext_vector_type(8))) short bf16x8;
typedef __attribute__((ext_vector_type(4))) float f32x4;
typedef __attribute__((ext_vector_type(4))) unsigned short u16x4;

// ---- ws float offsets ----
#define OFF_QB   0u            // f32 [8][2048][80]
#define OFF_OB   1310720u      // f32 [2048][640]
#define OFF_QH   2621440u      // bf16 [8][2048][96] (as 786432 floats)
#define OFF_QL   3407872u
#define OFF_KCH  4194304u
#define OFF_KSH  4980736u
#define OFF_KSL  5767168u
#define OFF_VCB  6553600u      // bf16 [8][2048][80] (655360 floats)
#define OFF_VCQ  7208960u
#define OFF_VSB  7864320u
#define OFF_VSQ  8519680u
#define OFF_OP   9175040u      // f32 [2][8][2048][80]
#define OFF_SP   11796480u
#define OFF_DEN  14417920u     // f32 [2][8][2048]
#define OFF_MSZ  14450688u
#define OFF_LSZ  14483456u
#define OFF_MCZ  14516224u
#define OFF_LCZ  14548992u
#define OFF_M    14581760u     // f32 [8][2048]
#define OFF_LAM  14598144u     // f32 [2048]
#define OFF_THR  14600192u     // u32 [8][2048]
#define OFF_MU   14616576u
#define OFF_RSTD 14617216u
#define OFF_S    14617856u     // f32 [8][2048][2048]

static __device__ __forceinline__ unsigned int sortkey(float x) {
  unsigned int b = __float_as_uint(x);
  return (b & 0x80000000u) ? ~b : (b | 0x80000000u);
}
static __device__ __forceinline__ unsigned short f2bf(float f) {
  unsigned u = __float_as_uint(f);
  return (unsigned short)((u + 0x7FFFu + ((u >> 16) & 1u)) >> 16);
}
static __device__ __forceinline__ float bf2f(unsigned short s) {
  return __uint_as_float(((unsigned)s) << 16);
}

// ---------------- split-bf16 MFMA projection GEMM ---------------------------
__global__ __launch_bounds__(256) void k_projmm(
    const float* __restrict__ x, const float* __restrict__ Wq,
    const float* __restrict__ Wk, const float* __restrict__ Wv,
    const float* __restrict__ Qc, float* __restrict__ qb,
    unsigned short* __restrict__ qh_, unsigned short* __restrict__ ql_,
    unsigned short* __restrict__ kch_,
    unsigned short* __restrict__ vcb_, unsigned short* __restrict__ vcq_)
{
  const float* W = (blockIdx.z == 0) ? Wq : ((blockIdx.z == 1) ? Wk : Wv);
  const int n0 = blockIdx.y * 64, c0 = blockIdx.x * 64;
  const int tid = threadIdx.x;
  const int w = tid >> 6, l = tid & 63;
  const int cc = l & 15, g = l >> 4;

  __shared__ unsigned short sXh[64 * 72];
  __shared__ unsigned short sXl[64 * 72];
  __shared__ unsigned short sWh[64 * 72];
  __shared__ unsigned short sWl[64 * 72];

  f32x4 D[4];
#pragma unroll
  for (int ct = 0; ct < 4; ++ct) D[ct] = (f32x4){0.f, 0.f, 0.f, 0.f};

  for (int k0 = 0; k0 < QD; k0 += 64) {
    __syncthreads();
#pragma unroll
    for (int it = 0; it < 4; ++it) {
      int f = tid + it * 256;           // float4 index in 64x64 tile
      int row = f >> 4, col4 = f & 15;
      float4 xa = *(const float4*)(x + (size_t)(n0 + row) * QD + k0 + col4 * 4);
      float4 wa = *(const float4*)(W + (size_t)(c0 + row) * QD + k0 + col4 * 4);
      u16x4 xh, xl, wh, wl;
      float xv[4] = {xa.x, xa.y, xa.z, xa.w};
      float wv[4] = {wa.x, wa.y, wa.z, wa.w};
#pragma unroll
      for (int j = 0; j < 4; ++j) {
        unsigned short h1 = f2bf(xv[j]);
        xh[j] = h1; xl[j] = f2bf(xv[j] - bf2f(h1));
        unsigned short h2 = f2bf(wv[j]);
        wh[j] = h2; wl[j] = f2bf(wv[j] - bf2f(h2));
      }
      *(u16x4*)&sXh[row * 72 + col4 * 4] = xh;
      *(u16x4*)&sXl[row * 72 + col4 * 4] = xl;
      *(u16x4*)&sWh[row * 72 + col4 * 4] = wh;
      *(u16x4*)&sWl[row * 72 + col4 * 4] = wl;
    }
    __syncthreads();
    bf16x8 ah[2], al[2];
#pragma unroll
    for (int kc = 0; kc < 2; ++kc) {
      ah[kc] = *(const bf16x8*)&sXh[(w * 16 + cc) * 72 + kc * 32 + g * 8];
      al[kc] = *(const bf16x8*)&sXl[(w * 16 + cc) * 72 + kc * 32 + g * 8];
    }
#pragma unroll
    for (int ct = 0; ct < 4; ++ct) {
#pragma unroll
      for (int kc = 0; kc < 2; ++kc) {
        bf16x8 bh = *(const bf16x8*)&sWh[(ct * 16 + cc) * 72 + kc * 32 + g * 8];
        bf16x8 bl = *(const bf16x8*)&sWl[(ct * 16 + cc) * 72 + kc * 32 + g * 8];
        D[ct] = __builtin_amdgcn_mfma_f32_16x16x32_bf16(ah[kc], bh, D[ct], 0, 0, 0);
        D[ct] = __builtin_amdgcn_mfma_f32_16x16x32_bf16(ah[kc], bl, D[ct], 0, 0, 0);
        D[ct] = __builtin_amdgcn_mfma_f32_16x16x32_bf16(al[kc], bh, D[ct], 0, 0, 0);
      }
    }
  }
  // epilogue
#pragma unroll
  for (int ct = 0; ct < 4; ++ct) {
#pragma unroll
    for (int r = 0; r < 4; ++r) {
      int n = n0 + w * 16 + g * 4 + r;
      int ccol = c0 + ct * 16 + cc;
      int h = ccol / DH, d = ccol - h * DH;
      size_t i80 = ((size_t)h * NTOK + n) * 80 + d;
      size_t i96 = ((size_t)h * NTOK + n) * 96 + d;
      float val = D[ct][r];
      if (blockIdx.z == 0) {
        val = GAMMA_F * Qc[i80] + (1.f - GAMMA_F) * val;
        qb[i80] = val;
        unsigned short hs = f2bf(val);
        qh_[i96] = hs;
        ql_[i96] = f2bf(val - bf2f(hs));
      } else if (blockIdx.z == 1) {
        kch_[i96] = f2bf(val);
      } else {
        vcb_[i80] = f2bf(val);
        vcq_[i80] = f2bf(val * val);
      }
    }
  }
}

// ---------------- style input conversion + pads -----------------------------
__global__ __launch_bounds__(384) void k_cvt(
    const float* __restrict__ Ks, const float* __restrict__ Vs,
    unsigned short* __restrict__ Ksh, unsigned short* __restrict__ Ksl,
    unsigned short* __restrict__ Vsb, unsigned short* __restrict__ Vsq,
    unsigned short* __restrict__ qh_, unsigned short* __restrict__ ql_,
    unsigned short* __restrict__ kch_)
{
  int h = blockIdx.y;
  int n = blockIdx.x * 4 + threadIdx.x / 96;
  int d = threadIdx.x % 96;
  size_t i80 = ((size_t)h * NTOK + n) * 80 + d;
  size_t i96 = ((size_t)h * NTOK + n) * 96 + d;
  if (d < 80) {
    float v = Ks[i80];
    unsigned short hs = f2bf(v);
    Ksh[i96] = hs; Ksl[i96] = f2bf(v - bf2f(hs));
    float vv = Vs[i80];
    Vsb[i80] = f2bf(vv); Vsq[i80] = f2bf(vv * vv);
  } else {
    Ksh[i96] = 0; Ksl[i96] = 0; qh_[i96] = 0; ql_[i96] = 0; kch_[i96] = 0;
  }
}

// ---------------- per-(h,d) mean / rstd of q over tokens --------------------
__global__ __launch_bounds__(128) void k_qstats(
    const float* __restrict__ qb, float* __restrict__ mu, float* __restrict__ rstd)
{
  const int h = blockIdx.x / DH, d = blockIdx.x % DH;
  const int tid = threadIdx.x;
  float s = 0.f, s2 = 0.f;
  for (int n = tid; n < NTOK; n += 128) {
    float v = qb[((size_t)h * NTOK + n) * 80 + d];
    s += v; s2 = fmaf(v, v, s2);
  }
#pragma unroll
  for (int off = 32; off; off >>= 1) { s += __shfl_xor(s, off, 64); s2 += __shfl_xor(s2, off, 64); }
  __shared__ float sh[4];
  if ((tid & 63) == 0) { sh[(tid >> 6) * 2] = s; sh[(tid >> 6) * 2 + 1] = s2; }
  __syncthreads();
  if (tid == 0) {
    float S = sh[0] + sh[2], S2 = sh[1] + sh[3];
    float mval = S * (1.f / NTOK);
    float var = S2 * (1.f / NTOK) - mval * mval;
    mu[h * DH + d] = mval;
    rstd[h * DH + d] = rsqrtf(var + 1e-5f);
  }
}

// ---------------- pass A: MFMA logits; store style S; per-row LSE -----------
__global__ __launch_bounds__(256) void k_passA(
    const unsigned short* __restrict__ qh_, const unsigned short* __restrict__ ql_,
    const unsigned short* __restrict__ Ksh, const unsigned short* __restrict__ Ksl,
    const unsigned short* __restrict__ kch_,
    float* __restrict__ S, float* __restrict__ mSz, float* __restrict__ lSz,
    float* __restrict__ mCz, float* __restrict__ lCz)
{
  const int h = blockIdx.y, z = blockIdx.z;
  const int q0 = blockIdx.x * 64;
  const int tid = threadIdx.x;
  const int w = tid >> 6, l = tid & 63;
  const int c = l & 15, g = l >> 4;

  __shared__ unsigned short sKh[64 * 104];
  __shared__ unsigned short sKl[64 * 104];

  bf16x8 qhf[3], qlf[3];
  {
    const size_t qrow = ((size_t)h * NTOK + q0 + w * 16 + c) * 96;
#pragma unroll
    for (int kc = 0; kc < 3; ++kc) {
      qhf[kc] = *(const bf16x8*)(qh_ + qrow + kc * 32 + g * 8);
      qlf[kc] = *(const bf16x8*)(ql_ + qrow + kc * 32 + g * 8);
    }
  }
  float m[4], lse[4], mc[4], lc[4];
#pragma unroll
  for (int r = 0; r < 4; ++r) { m[r] = -INFINITY; lse[r] = 0.f; mc[r] = -INFINITY; lc[r] = 0.f; }

  // ---- style: 16 key tiles of 64 ----
  for (int t = 0; t < 16; ++t) {
    const size_t kbase = ((size_t)h * NTOK + z * 1024 + t * 64) * 96;
    __syncthreads();
    for (int f = tid; f < 768; f += 256) {
      int row = f / 12, ch = f % 12;
      *(bf16x8*)(sKh + row * 104 + ch * 8) = *(const bf16x8*)(Ksh + kbase + row * 96 + ch * 8);
      *(bf16x8*)(sKl + row * 104 + ch * 8) = *(const bf16x8*)(Ksl + kbase + row * 96 + ch * 8);
    }
    __syncthreads();
#pragma unroll
    for (int ct = 0; ct < 4; ++ct) {
      f32x4 D = {0.f, 0.f, 0.f, 0.f};
      const int krow = (ct * 16 + c) * 104 + g * 8;
#pragma unroll
      for (int kc = 0; kc < 3; ++kc) {
        bf16x8 bh = *(const bf16x8*)(sKh + krow + kc * 32);
        D = __builtin_amdgcn_mfma_f32_16x16x32_bf16(qhf[kc], bh, D, 0, 0, 0);
      }
#pragma unroll
      for (int kc = 0; kc < 3; ++kc) {
        bf16x8 bl = *(const bf16x8*)(sKl + krow + kc * 32);
        D = __builtin_amdgcn_mfma_f32_16x16x32_bf16(qhf[kc], bl, D, 0, 0, 0);
      }
#pragma unroll
      for (int kc = 0; kc < 3; ++kc) {
        bf16x8 bh = *(const bf16x8*)(sKh + krow + kc * 32);
        D = __builtin_amdgcn_mfma_f32_16x16x32_bf16(qlf[kc], bh, D, 0, 0, 0);
      }
#pragma unroll
      for (int r = 0; r < 4; ++r) {
        float s = D[r] * TSCALE_F;
        S[((size_t)h * NTOK + q0 + w * 16 + g * 4 + r) * 2048 + z * 1024 + t * 64 + ct * 16 + c] = s;
        float mn = fmaxf(m[r], s);
        lse[r] = lse[r] * __expf(m[r] - mn) + __expf(s - mn);
        m[r] = mn;
      }
    }
  }
  // ---- content: 16 key tiles ----
  for (int t = 0; t < 16; ++t) {
    const size_t kbase = ((size_t)h * NTOK + z * 1024 + t * 64) * 96;
    __syncthreads();
    for (int f = tid; f < 768; f += 256) {
      int row = f / 12, ch = f % 12;
      *(bf16x8*)(sKh + row * 104 + ch * 8) = *(const bf16x8*)(kch_ + kbase + row * 96 + ch * 8);
    }
    __syncthreads();
#pragma unroll
    for (int ct = 0; ct < 4; ++ct) {
      f32x4 D = {0.f, 0.f, 0.f, 0.f};
      const int krow = (ct * 16 + c) * 104 + g * 8;
#pragma unroll
      for (int kc = 0; kc < 3; ++kc) {
        bf16x8 bh = *(const bf16x8*)(sKh + krow + kc * 32);
        D = __builtin_amdgcn_mfma_f32_16x16x32_bf16(qhf[kc], bh, D, 0, 0, 0);
      }
#pragma unroll
      for (int r = 0; r < 4; ++r) {
        float s = D[r] * SCALE_F;
        float mn = fmaxf(mc[r], s);
        lc[r] = lc[r] * __expf(mc[r] - mn) + __expf(s - mn);
        mc[r] = mn;
      }
    }
  }
  // merge across the 16 col-lanes
#pragma unroll
  for (int off = 1; off < 16; off <<= 1) {
#pragma unroll
    for (int r = 0; r < 4; ++r) {
      float mo = __shfl_xor(m[r], off, 64), lo = __shfl_xor(lse[r], off, 64);
      float mn = fmaxf(m[r], mo);
      lse[r] = lse[r] * __expf(m[r] - mn) + lo * __expf(mo - mn);
      m[r] = mn;
      float mo2 = __shfl_xor(mc[r], off, 64), lo2 = __shfl_xor(lc[r], off, 64);
      float mn2 = fmaxf(mc[r], mo2);
      lc[r] = lc[r] * __expf(mc[r] - mn2) + lo2 * __expf(mo2 - mn2);
      mc[r] = mn2;
    }
  }
  if (c == 0) {
    size_t base = (size_t)(z * 8 + h) * NTOK + q0 + w * 16 + g * 4;
#pragma unroll
    for (int r = 0; r < 4; ++r) {
      mSz[base + r] = m[r]; lSz[base + r] = lse[r];
      mCz[base + r] = mc[r]; lCz[base + r] = lc[r];
    }
  }
}

// ---------------- gate: combine z-halves, lambda, M --------------------------
__global__ __launch_bounds__(256) void k_gate(
    const float* __restrict__ mSz, const float* __restrict__ lSz,
    const float* __restrict__ mCz, const float* __restrict__ lCz,
    float* __restrict__ M_, float* __restrict__ lam_)
{
  int n = blockIdx.x * 256 + threadIdx.x;
  if (n >= NTOK) return;
  float msf[NH], mcf[NH], sum = 0.f;
#pragma unroll
  for (int h = 0; h < NH; ++h) {
    float m0 = mSz[(size_t)(0 * 8 + h) * NTOK + n], m1 = mSz[(size_t)(8 + h) * NTOK + n];
    float l0 = lSz[(size_t)(0 * 8 + h) * NTOK + n], l1 = lSz[(size_t)(8 + h) * NTOK + n];
    float mm = fmaxf(m0, m1);
    float lse_s = mm + __logf(l0 * __expf(m0 - mm) + l1 * __expf(m1 - mm));
    float c0 = mCz[(size_t)(0 * 8 + h) * NTOK + n], c1 = mCz[(size_t)(8 + h) * NTOK + n];
    float d0 = lCz[(size_t)(0 * 8 + h) * NTOK + n], d1 = lCz[(size_t)(8 + h) * NTOK + n];
    float cm = fmaxf(c0, c1);
    float lse_c = cm + __logf(d0 * __expf(c0 - cm) + d1 * __expf(c1 - cm));
    msf[h] = mm; mcf[h] = cm;
    sum += fminf(fmaxf(lse_s - lse_c, -20.f), 20.f);
  }
  float lam = 1.f + (LMAX_F - 1.f) * (1.f / (1.f + __expf(-sum * (1.f / NH))));
  lam_[n] = lam;
#pragma unroll
  for (int h = 0; h < NH; ++h)
    M_[h * NTOK + n] = fmaxf(lam * msf[h], mcf[h]);
}

// ---------------- top-k threshold: ballot-count bisection -------------------
__global__ __launch_bounds__(512) void k_topk(const float* __restrict__ S,
                                              unsigned* __restrict__ thr_)
{
  const int h = blockIdx.y;
  const int n = blockIdx.x * 8 + (threadIdx.x >> 6);
  const int l = threadIdx.x & 63;
  const float* Srow = S + ((size_t)h * NTOK + n) * 2048;
  unsigned kv[32];
#pragma unroll
  for (int t = 0; t < 8; ++t) {
    float4 v = ((const float4*)Srow)[t * 64 + l];
    kv[t * 4 + 0] = sortkey(v.x); kv[t * 4 + 1] = sortkey(v.y);
    kv[t * 4 + 2] = sortkey(v.z); kv[t * 4 + 3] = sortkey(v.w);
  }
  unsigned klo = 0u, khi = 0xFFFFFFFFu;
  for (int it = 0; it < 32; ++it) {
    unsigned mid = klo + ((khi - klo) >> 1);
    int cnt = 0;
#pragma unroll
    for (int t = 0; t < 32; ++t)
      cnt += __popcll(__ballot(kv[t] >= mid));
    if (cnt == TOPKN) { klo = mid; break; }       // exactly top-128 selected
    if (cnt > TOPKN) klo = mid; else khi = mid;
    if (khi - klo <= 1u) break;
  }
  if (l == 0) thr_[h * NTOK + n] = klo;
}

// ---------------- pass B: recompute logits (bit-identical), P + PV MFMA -----
// No S read: style logits recomputed with the EXACT passA MFMA sequence so
// sortkey(s) vs thr_ comparisons are bit-consistent with k_topk's input.
__global__ __launch_bounds__(256) void k_passB(
    const unsigned short* __restrict__ qh_, const unsigned short* __restrict__ ql_,
    const unsigned short* __restrict__ Ksh, const unsigned short* __restrict__ Ksl,
    const unsigned short* __restrict__ kch_,
    const unsigned short* __restrict__ Vsb, const unsigned short* __restrict__ Vsq,
    const unsigned short* __restrict__ vcb, const unsigned short* __restrict__ vcq,
    const float* __restrict__ M_, const float* __restrict__ lam_,
    const unsigned* __restrict__ thr_,
    float* __restrict__ oP, float* __restrict__ sP, float* __restrict__ denP)
{
  const int h = blockIdx.y, z = blockIdx.z;
  const int q0 = blockIdx.x * 64;
  const int tid = threadIdx.x;
  const int w = tid >> 6, l = tid & 63;
  const int c = l & 15, g = l >> 4;

  __shared__ char arena[49664];
  unsigned short* sKh   = (unsigned short*)arena;            // [64][104]
  unsigned short* sKl   = (unsigned short*)(arena + 13312);  // [64][104]
  unsigned short* P_lds = (unsigned short*)(arena + 13312);  // alias: [4][16][72]
  unsigned short* vT    = (unsigned short*)(arena + 26624);  // [80][72]
  unsigned short* vqT   = (unsigned short*)(arena + 38144);  // [80][72]
  __shared__ float Mr[64], lamr[64], den_l[64];
  __shared__ unsigned thrr[64];

  if (tid < 64) {
    int n = q0 + tid;
    Mr[tid] = M_[h * NTOK + n];
    lamr[tid] = lam_[n];
    thrr[tid] = thr_[h * NTOK + n];
  }
  bf16x8 qhf[3], qlf[3];
  {
    const size_t qrow = ((size_t)h * NTOK + q0 + w * 16 + c) * 96;
#pragma unroll
    for (int kc = 0; kc < 3; ++kc) {
      qhf[kc] = *(const bf16x8*)(qh_ + qrow + kc * 32 + g * 8);
      qlf[kc] = *(const bf16x8*)(ql_ + qrow + kc * 32 + g * 8);
    }
  }
  __syncthreads();
  // per-lane row params, C-layout rows w*16+g*4+r
  float myM4[4], myLam4[4];
  unsigned myThr4[4];
#pragma unroll
  for (int r = 0; r < 4; ++r) {
    myM4[r] = Mr[w * 16 + g * 4 + r];
    myLam4[r] = lamr[w * 16 + g * 4 + r];
    myThr4[r] = thrr[w * 16 + g * 4 + r];
  }

  f32x4 oacc[5], sacc[5];
#pragma unroll
  for (int dt = 0; dt < 5; ++dt) { oacc[dt] = (f32x4){0.f,0.f,0.f,0.f}; sacc[dt] = (f32x4){0.f,0.f,0.f,0.f}; }
  float den4[4] = {0.f, 0.f, 0.f, 0.f};

  // ---- style tiles: recompute s (bit-identical to passA), threshold, PV ----
  for (int t = 0; t < 16; ++t) {
    const int k0 = z * 1024 + t * 64;
    const size_t kbase = ((size_t)h * NTOK + k0) * 96;
    __syncthreads();   // prev tile P/vT reads done
    for (int f = tid; f < 768; f += 256) {
      int row = f / 12, ch = f % 12;
      *(bf16x8*)(sKh + row * 104 + ch * 8) = *(const bf16x8*)(Ksh + kbase + row * 96 + ch * 8);
      *(bf16x8*)(sKl + row * 104 + ch * 8) = *(const bf16x8*)(Ksl + kbase + row * 96 + ch * 8);
    }
    for (int f = tid; f < 320; f += 256) {
      int kp = f & 31, ch = f >> 5;
      const size_t vb = ((size_t)h * NTOK + k0 + kp * 2) * 80 + ch * 8;
      bf16x8 a = *(const bf16x8*)(Vsb + vb);
      bf16x8 b = *(const bf16x8*)(Vsb + vb + 80);
      bf16x8 aq = *(const bf16x8*)(Vsq + vb);
      bf16x8 bq = *(const bf16x8*)(Vsq + vb + 80);
#pragma unroll
      for (int j = 0; j < 8; ++j) {
        int d = ch * 8 + j;
        *(unsigned*)&vT[d * 72 + kp * 2]  = ((unsigned)(unsigned short)b[j] << 16) | (unsigned short)a[j];
        *(unsigned*)&vqT[d * 72 + kp * 2] = ((unsigned)(unsigned short)bq[j] << 16) | (unsigned short)aq[j];
      }
    }
    __syncthreads();
    unsigned short pv[4][4];
#pragma unroll
    for (int ct = 0; ct < 4; ++ct) {
      f32x4 D = {0.f, 0.f, 0.f, 0.f};
      const int krow = (ct * 16 + c) * 104 + g * 8;
#pragma unroll
      for (int kc = 0; kc < 3; ++kc) {
        bf16x8 bh = *(const bf16x8*)(sKh + krow + kc * 32);
        D = __builtin_amdgcn_mfma_f32_16x16x32_bf16(qhf[kc], bh, D, 0, 0, 0);
      }
#pragma unroll
      for (int kc = 0; kc < 3; ++kc) {
        bf16x8 bl = *(const bf16x8*)(sKl + krow + kc * 32);
        D = __builtin_amdgcn_mfma_f32_16x16x32_bf16(qhf[kc], bl, D, 0, 0, 0);
      }
#pragma unroll
      for (int kc = 0; kc < 3; ++kc) {
        bf16x8 bh = *(const bf16x8*)(sKh + krow + kc * 32);
        D = __builtin_amdgcn_mfma_f32_16x16x32_bf16(qlf[kc], bh, D, 0, 0, 0);
      }
#pragma unroll
      for (int r = 0; r < 4; ++r) {
        float s = D[r] * TSCALE_F;
        float wv = (sortkey(s) >= myThr4[r]) ? __expf(myLam4[r] * s - myM4[r]) : 0.f;
        den4[r] += wv;
        pv[ct][r] = f2bf(wv);
      }
    }
    __syncthreads();   // all sKl reads done before P overwrite
#pragma unroll
    for (int ct = 0; ct < 4; ++ct)
#pragma unroll
      for (int r = 0; r < 4; ++r)
        P_lds[w * 1152 + (g * 4 + r) * 72 + ct * 16 + c] = pv[ct][r];
    __syncthreads();
    bf16x8 pa0 = *(const bf16x8*)(P_lds + w * 1152 + c * 72 + g * 8);
    bf16x8 pa1 = *(const bf16x8*)(P_lds + w * 1152 + c * 72 + 32 + g * 8);
#pragma unroll
    for (int dt = 0; dt < 5; ++dt) {
      bf16x8 bv0  = *(const bf16x8*)&vT[(dt * 16 + c) * 72 + g * 8];
      bf16x8 bvq0 = *(const bf16x8*)&vqT[(dt * 16 + c) * 72 + g * 8];
      bf16x8 bv1  = *(const bf16x8*)&vT[(dt * 16 + c) * 72 + 32 + g * 8];
      bf16x8 bvq1 = *(const bf16x8*)&vqT[(dt * 16 + c) * 72 + 32 + g * 8];
      oacc[dt] = __builtin_amdgcn_mfma_f32_16x16x32_bf16(pa0, bv0, oacc[dt], 0, 0, 0);
      sacc[dt] = __builtin_amdgcn_mfma_f32_16x16x32_bf16(pa0, bvq0, sacc[dt], 0, 0, 0);
      oacc[dt] = __builtin_amdgcn_mfma_f32_16x16x32_bf16(pa1, bv1, oacc[dt], 0, 0, 0);
      sacc[dt] = __builtin_amdgcn_mfma_f32_16x16x32_bf16(pa1, bvq1, sacc[dt], 0, 0, 0);
    }
  }
  // ---- content tiles: recompute logits, P via LDS ----
  for (int t = 0; t < 16; ++t) {
    const int k0 = z * 1024 + t * 64;
    __syncthreads();
    for (int f = tid; f < 768; f += 256) {
      int row = f / 12, ch = f % 12;
      *(bf16x8*)(sKh + row * 104 + ch * 8) =
          *(const bf16x8*)(kch_ + ((size_t)h * NTOK + k0 + row) * 96 + ch * 8);
    }
    for (int f = tid; f < 320; f += 256) {
      int kp = f & 31, ch = f >> 5;
      const size_t vb = ((size_t)h * NTOK + k0 + kp * 2) * 80 + ch * 8;
      bf16x8 a = *(const bf16x8*)(vcb + vb);
      bf16x8 b = *(const bf16x8*)(vcb + vb + 80);
      bf16x8 aq = *(const bf16x8*)(vcq + vb);
      bf16x8 bq = *(const bf16x8*)(vcq + vb + 80);
#pragma unroll
      for (int j = 0; j < 8; ++j) {
        int d = ch * 8 + j;
        *(unsigned*)&vT[d * 72 + kp * 2]  = ((unsigned)(unsigned short)b[j] << 16) | (unsigned short)a[j];
        *(unsigned*)&vqT[d * 72 + kp * 2] = ((unsigned)(unsigned short)bq[j] << 16) | (unsigned short)aq[j];
      }
    }
    __syncthreads();
#pragma unroll
    for (int ct = 0; ct < 4; ++ct) {
      f32x4 D = {0.f, 0.f, 0.f, 0.f};
      const int krow = (ct * 16 + c) * 104 + g * 8;
#pragma unroll
      for (int kc = 0; kc < 3; ++kc) {
        bf16x8 bh = *(const bf16x8*)(sKh + krow + kc * 32);
        D = __builtin_amdgcn_mfma_f32_16x16x32_bf16(qhf[kc], bh, D, 0, 0, 0);
      }
#pragma unroll
      for (int r = 0; r < 4; ++r) {
        float s = D[r] * SCALE_F;
        float wv = __expf(s - myM4[r]);
        den4[r] += wv;
        P_lds[w * 1152 + (g * 4 + r) * 72 + ct * 16 + c] = f2bf(wv);
      }
    }
    __syncthreads();
    bf16x8 pa0 = *(const bf16x8*)(P_lds + w * 1152 + c * 72 + g * 8);
    bf16x8 pa1 = *(const bf16x8*)(P_lds + w * 1152 + c * 72 + 32 + g * 8);
#pragma unroll
    for (int dt = 0; dt < 5; ++dt) {
      bf16x8 bv0  = *(const bf16x8*)&vT[(dt * 16 + c) * 72 + g * 8];
      bf16x8 bvq0 = *(const bf16x8*)&vqT[(dt * 16 + c) * 72 + g * 8];
      bf16x8 bv1  = *(const bf16x8*)&vT[(dt * 16 + c) * 72 + 32 + g * 8];
      bf16x8 bvq1 = *(const bf16x8*)&vqT[(dt * 16 + c) * 72 + 32 + g * 8];
      oacc[dt] = __builtin_amdgcn_mfma_f32_16x16x32_bf16(pa0, bv0, oacc[dt], 0, 0, 0);
      sacc[dt] = __builtin_amdgcn_mfma_f32_16x16x32_bf16(pa0, bvq0, sacc[dt], 0, 0, 0);
      oacc[dt] = __builtin_amdgcn_mfma_f32_16x16x32_bf16(pa1, bv1, oacc[dt], 0, 0, 0);
      sacc[dt] = __builtin_amdgcn_mfma_f32_16x16x32_bf16(pa1, bvq1, sacc[dt], 0, 0, 0);
    }
  }
  // ---- denominators: reduce over 16 col-lanes, direct store ----
#pragma unroll
  for (int off = 1; off < 16; off <<= 1)
#pragma unroll
    for (int r = 0; r < 4; ++r) den4[r] += __shfl_xor(den4[r], off, 64);
  if (c == 0) {
#pragma unroll
    for (int r = 0; r < 4; ++r) den_l[w * 16 + g * 4 + r] = den4[r];
  }
  __syncthreads();
  const size_t base = (size_t)(z * 8 + h) * NTOK + q0 + w * 16;
#pragma unroll
  for (int dt = 0; dt < 5; ++dt)
#pragma unroll
    for (int r = 0; r < 4; ++r) {
      size_t o = (base + g * 4 + r) * 80 + dt * 16 + c;
      oP[o] = oacc[dt][r];
      sP[o] = sacc[dt][r];
    }
  if (tid < 64) denP[(size_t)(z * 8 + h) * NTOK + q0 + tid] = den_l[tid];
}

// ---------------- finalize: combine halves + AdaIN epilogue -----------------
__global__ __launch_bounds__(256) void k_fin(
    const float* __restrict__ oP, const float* __restrict__ sP,
    const float* __restrict__ denP, const float* __restrict__ qb,
    const float* __restrict__ mu, const float* __restrict__ rstd,
    const float* __restrict__ gate, float* __restrict__ Ob)
{
  int idx = blockIdx.x * 256 + threadIdx.x;
  int h = idx / (NTOK * 80);
  int rem = idx - h * (NTOK * 80);
  int n = rem / 80, d = rem - n * 80;
  float den = denP[(size_t)h * NTOK + n] + denP[(size_t)(8 + h) * NTOK + n];
  size_t p0 = ((size_t)h * NTOK + n) * 80 + d;
  size_t p1 = ((size_t)(8 + h) * NTOK + n) * 80 + d;
  float o = (oP[p0] + oP[p1]) / den;
  float sq = (sP[p0] + sP[p1]) / den;
  float vstd = sqrtf(fmaxf(sq - o * o, 1e-5f));
  float g = tanhf(gate[0]);
  float qn = (qb[p0] - mu[h * DH + d]) * rstd[h * DH + d];
  Ob[(size_t)n * QD + h * DH + d] = fmaf(g * vstd, qn, o);
}

// ---------------- final projection: split-bf16 MFMA, out = Ob@Wo^T + bo -----
__global__ __launch_bounds__(256) void k_finalmm(
    const float* __restrict__ A, const float* __restrict__ W,
    const float* __restrict__ bias, float* __restrict__ out)
{
  const int n0 = blockIdx.y * 64, c0 = blockIdx.x * 64;
  const int tid = threadIdx.x;
  const int w = tid >> 6, l = tid & 63;
  const int cc = l & 15, g = l >> 4;

  __shared__ unsigned short sXh[64 * 72];
  __shared__ unsigned short sXl[64 * 72];
  __shared__ unsigned short sWh[64 * 72];
  __shared__ unsigned short sWl[64 * 72];

  f32x4 D[4];
#pragma unroll
  for (int ct = 0; ct < 4; ++ct) D[ct] = (f32x4){0.f, 0.f, 0.f, 0.f};

  for (int k0 = 0; k0 < QD; k0 += 64) {
    __syncthreads();
#pragma unroll
    for (int it = 0; it < 4; ++it) {
      int f = tid + it * 256;
      int row = f >> 4, col4 = f & 15;
      float4 xa = *(const float4*)(A + (size_t)(n0 + row) * QD + k0 + col4 * 4);
      float4 wa = *(const float4*)(W + (size_t)(c0 + row) * QD + k0 + col4 * 4);
      u16x4 xh, xl, wh, wl;
      float xv[4] = {xa.x, xa.y, xa.z, xa.w};
      float wv[4] = {wa.x, wa.y, wa.z, wa.w};
#pragma unroll
      for (int j = 0; j < 4; ++j) {
        unsigned short h1 = f2bf(xv[j]);
        xh[j] = h1; xl[j] = f2bf(xv[j] - bf2f(h1));
        unsigned short h2 = f2bf(wv[j]);
        wh[j] = h2; wl[j] = f2bf(wv[j] - bf2f(h2));
      }
      *(u16x4*)&sXh[row * 72 + col4 * 4] = xh;
      *(u16x4*)&sXl[row * 72 + col4 * 4] = xl;
      *(u16x4*)&sWh[row * 72 + col4 * 4] = wh;
      *(u16x4*)&sWl[row * 72 + col4 * 4] = wl;
    }
    __syncthreads();
    bf16x8 ah[2], al[2];
#pragma unroll
    for (int kc = 0; kc < 2; ++kc) {
      ah[kc] = *(const bf16x8*)&sXh[(w * 16 + cc) * 72 + kc * 32 + g * 8];
      al[kc] = *(const bf16x8*)&sXl[(w * 16 + cc) * 72 + kc * 32 + g * 8];
    }
#pragma unroll
    for (int ct = 0; ct < 4; ++ct) {
#pragma unroll
      for (int kc = 0; kc < 2; ++kc) {
        bf16x8 bh = *(const bf16x8*)&sWh[(ct * 16 + cc) * 72 + kc * 32 + g * 8];
        bf16x8 bl = *(const bf16x8*)&sWl[(ct * 16 + cc) * 72 + kc * 32 + g * 8];
        D[ct] = __builtin_amdgcn_mfma_f32_16x16x32_bf16(ah[kc], bh, D[ct], 0, 0, 0);
        D[ct] = __builtin_amdgcn_mfma_f32_16x16x32_bf16(ah[kc], bl, D[ct], 0, 0, 0);
        D[ct] = __builtin_amdgcn_mfma_f32_16x16x32_bf16(al[kc], bh, D[ct], 0, 0, 0);
      }
    }
  }
#pragma unroll
  for (int ct = 0; ct < 4; ++ct) {
#pragma unroll
    for (int r = 0; r < 4; ++r) {
      int n = n0 + w * 16 + g * 4 + r;
      int ccol = c0 + ct * 16 + cc;
      out[(size_t)n * QD + ccol] = D[ct][r] + bias[ccol];
    }
  }
}

extern "C" void kernel_launch(void* const* d_in, const int* in_sizes, int n_in,
                              void* d_out, int out_size, void* d_ws, size_t ws_size,
                              hipStream_t stream) {
  const float* x    = (const float*)d_in[0];
  const float* Qc   = (const float*)d_in[1];
  const float* Ks   = (const float*)d_in[2];
  const float* Vs   = (const float*)d_in[3];
  const float* Wq   = (const float*)d_in[4];
  const float* Wk   = (const float*)d_in[5];
  const float* Wv   = (const float*)d_in[6];
  const float* Wo   = (const float*)d_in[7];
  const float* bo   = (const float*)d_in[8];
  const float* gate = (const float*)d_in[9];
  float* out = (float*)d_out;
  float* w = (float*)d_ws;

  float* qb   = w + OFF_QB;
  float* Ob   = w + OFF_OB;
  unsigned short* qh_  = (unsigned short*)(w + OFF_QH);
  unsigned short* ql_  = (unsigned short*)(w + OFF_QL);
  unsigned short* kch_ = (unsigned short*)(w + OFF_KCH);
  unsigned short* Ksh  = (unsigned short*)(w + OFF_KSH);
  unsigned short* Ksl  = (unsigned short*)(w + OFF_KSL);
  unsigned short* vcb  = (unsigned short*)(w + OFF_VCB);
  unsigned short* vcq  = (unsigned short*)(w + OFF_VCQ);
  unsigned short* Vsb  = (unsigned short*)(w + OFF_VSB);
  unsigned short* Vsq  = (unsigned short*)(w + OFF_VSQ);
  float* oP   = w + OFF_OP;
  float* sP   = w + OFF_SP;
  float* denP = w + OFF_DEN;
  float* mSz  = w + OFF_MSZ;
  float* lSz  = w + OFF_LSZ;
  float* mCz  = w + OFF_MCZ;
  float* lCz  = w + OFF_LCZ;
  float* M_   = w + OFF_M;
  float* lam_ = w + OFF_LAM;
  unsigned* thr_ = (unsigned*)(w + OFF_THR);
  float* mu   = w + OFF_MU;
  float* rstd = w + OFF_RSTD;
  float* S    = w + OFF_S;

  k_projmm<<<dim3(10, 32, 3), 256, 0, stream>>>(x, Wq, Wk, Wv, Qc, qb, qh_, ql_, kch_, vcb, vcq);
  k_cvt<<<dim3(512, 8), 384, 0, stream>>>(Ks, Vs, Ksh, Ksl, Vsb, Vsq, qh_, ql_, kch_);
  k_qstats<<<dim3(640), 128, 0, stream>>>(qb, mu, rstd);
  k_passA<<<dim3(32, 8, 2), 256, 0, stream>>>(qh_, ql_, Ksh, Ksl, kch_, S, mSz, lSz, mCz, lCz);
  k_gate<<<dim3(8), 256, 0, stream>>>(mSz, lSz, mCz, lCz, M_, lam_);
  k_topk<<<dim3(256, 8), 512, 0, stream>>>(S, thr_);
  k_passB<<<dim3(32, 8, 2), 256, 0, stream>>>(qh_, ql_, Ksh, Ksl, kch_, Vsb, Vsq, vcb, vcq, M_, lam_, thr_, oP, sP, denP);
  k_fin<<<dim3(5120), 256, 0, stream>>>(oP, sP, denP, qb, mu, rstd, gate, Ob);
  k_finalmm<<<dim3(10, 32), 256, 0, stream>>>(Ob, Wo, bo, out);
}

// Round 7
// 293.647 us; speedup vs baseline: 1.2098x; 1.2098x over previous
//
#include <hip/hip_runtime.h>
#include <hip/hip_fp16.h>
#include <math.h>

#define NH 8
#define DH 80
#define NTOK 2048
#define QD 640
#define SCALE_F 0.11180339887498949f
#define TSCALE_F (1.2f * SCALE_F)
#define GAMMA_F 0.3f
#define LMAX_F 2.5f
#define TOPKN 128

typedef __attribute__((ext_vector_type(8))) short bf16x8;
typedef __attribute__((ext_vector_type(4))) float f32x4;
typedef __attribute__((ext_vector_type(4))) unsigned short u16x4;

// ---- ws float offsets ----
#define OFF_QB   0u            // f32 [8][2048][80]
#define OFF_OB   1310720u      // f32 [2048][640]
#define OFF_QH   2621440u      // bf16 [8][2048][96]
#define OFF_QL   3407872u
#define OFF_KCH  4194304u
#define OFF_KSH  4980736u
#define OFF_KSL  5767168u
#define OFF_VCB  6553600u      // bf16 [8][2048][80]
#define OFF_VCQ  7208960u
#define OFF_VSB  7864320u
#define OFF_VSQ  8519680u
#define OFF_OP   9175040u      // f32 [4][8][2048][80] = 5242880
#define OFF_SP   14417920u     // f32 [4][8][2048][80]
#define OFF_DEN  19660800u     // f32 [4][8][2048]
#define OFF_MSZ  19726336u     // f32 [4][8][2048]
#define OFF_LSZ  19791872u
#define OFF_MCZ  19857408u
#define OFF_LCZ  19922944u
#define OFF_M    19988480u     // f32 [8][2048]
#define OFF_LAM  20004864u     // f32 [2048]
#define OFF_THR  20006912u     // u32 [8][2048]
#define OFF_MU   20023296u
#define OFF_RSTD 20023936u
#define OFF_S16  20024576u     // fp16 [8][2048][2048] = 16777216 floats

static __device__ __forceinline__ unsigned short f2bf(float f) {
  unsigned u = __float_as_uint(f);
  return (unsigned short)((u + 0x7FFFu + ((u >> 16) & 1u)) >> 16);
}
static __device__ __forceinline__ float bf2f(unsigned short s) {
  return __uint_as_float(((unsigned)s) << 16);
}
static __device__ __forceinline__ unsigned sk16(unsigned u) {
  return (u & 0x8000u) ? (~u & 0xFFFFu) : (u | 0x8000u);
}

// ---------------- split-bf16 MFMA projection GEMM ---------------------------
__global__ __launch_bounds__(256) void k_projmm(
    const float* __restrict__ x, const float* __restrict__ Wq,
    const float* __restrict__ Wk, const float* __restrict__ Wv,
    const float* __restrict__ Qc, float* __restrict__ qb,
    unsigned short* __restrict__ qh_, unsigned short* __restrict__ ql_,
    unsigned short* __restrict__ kch_,
    unsigned short* __restrict__ vcb_, unsigned short* __restrict__ vcq_)
{
  const float* W = (blockIdx.z == 0) ? Wq : ((blockIdx.z == 1) ? Wk : Wv);
  const int n0 = blockIdx.y * 64, c0 = blockIdx.x * 64;
  const int tid = threadIdx.x;
  const int w = tid >> 6, l = tid & 63;
  const int cc = l & 15, g = l >> 4;

  __shared__ unsigned short sXh[64 * 72];
  __shared__ unsigned short sXl[64 * 72];
  __shared__ unsigned short sWh[64 * 72];
  __shared__ unsigned short sWl[64 * 72];

  f32x4 D[4];
#pragma unroll
  for (int ct = 0; ct < 4; ++ct) D[ct] = (f32x4){0.f, 0.f, 0.f, 0.f};

  for (int k0 = 0; k0 < QD; k0 += 64) {
    __syncthreads();
#pragma unroll
    for (int it = 0; it < 4; ++it) {
      int f = tid + it * 256;
      int row = f >> 4, col4 = f & 15;
      float4 xa = *(const float4*)(x + (size_t)(n0 + row) * QD + k0 + col4 * 4);
      float4 wa = *(const float4*)(W + (size_t)(c0 + row) * QD + k0 + col4 * 4);
      u16x4 xh, xl, wh, wl;
      float xv[4] = {xa.x, xa.y, xa.z, xa.w};
      float wv[4] = {wa.x, wa.y, wa.z, wa.w};
#pragma unroll
      for (int j = 0; j < 4; ++j) {
        unsigned short h1 = f2bf(xv[j]);
        xh[j] = h1; xl[j] = f2bf(xv[j] - bf2f(h1));
        unsigned short h2 = f2bf(wv[j]);
        wh[j] = h2; wl[j] = f2bf(wv[j] - bf2f(h2));
      }
      *(u16x4*)&sXh[row * 72 + col4 * 4] = xh;
      *(u16x4*)&sXl[row * 72 + col4 * 4] = xl;
      *(u16x4*)&sWh[row * 72 + col4 * 4] = wh;
      *(u16x4*)&sWl[row * 72 + col4 * 4] = wl;
    }
    __syncthreads();
    bf16x8 ah[2], al[2];
#pragma unroll
    for (int kc = 0; kc < 2; ++kc) {
      ah[kc] = *(const bf16x8*)&sXh[(w * 16 + cc) * 72 + kc * 32 + g * 8];
      al[kc] = *(const bf16x8*)&sXl[(w * 16 + cc) * 72 + kc * 32 + g * 8];
    }
#pragma unroll
    for (int ct = 0; ct < 4; ++ct) {
#pragma unroll
      for (int kc = 0; kc < 2; ++kc) {
        bf16x8 bh = *(const bf16x8*)&sWh[(ct * 16 + cc) * 72 + kc * 32 + g * 8];
        bf16x8 bl = *(const bf16x8*)&sWl[(ct * 16 + cc) * 72 + kc * 32 + g * 8];
        D[ct] = __builtin_amdgcn_mfma_f32_16x16x32_bf16(ah[kc], bh, D[ct], 0, 0, 0);
        D[ct] = __builtin_amdgcn_mfma_f32_16x16x32_bf16(ah[kc], bl, D[ct], 0, 0, 0);
        D[ct] = __builtin_amdgcn_mfma_f32_16x16x32_bf16(al[kc], bh, D[ct], 0, 0, 0);
      }
    }
  }
#pragma unroll
  for (int ct = 0; ct < 4; ++ct) {
#pragma unroll
    for (int r = 0; r < 4; ++r) {
      int n = n0 + w * 16 + g * 4 + r;
      int ccol = c0 + ct * 16 + cc;
      int h = ccol / DH, d = ccol - h * DH;
      size_t i80 = ((size_t)h * NTOK + n) * 80 + d;
      size_t i96 = ((size_t)h * NTOK + n) * 96 + d;
      float val = D[ct][r];
      if (blockIdx.z == 0) {
        val = GAMMA_F * Qc[i80] + (1.f - GAMMA_F) * val;
        qb[i80] = val;
        unsigned short hs = f2bf(val);
        qh_[i96] = hs;
        ql_[i96] = f2bf(val - bf2f(hs));
      } else if (blockIdx.z == 1) {
        kch_[i96] = f2bf(val);
      } else {
        vcb_[i80] = f2bf(val);
        vcq_[i80] = f2bf(val * val);
      }
    }
  }
}

// ---------------- style input conversion + pads -----------------------------
__global__ __launch_bounds__(384) void k_cvt(
    const float* __restrict__ Ks, const float* __restrict__ Vs,
    unsigned short* __restrict__ Ksh, unsigned short* __restrict__ Ksl,
    unsigned short* __restrict__ Vsb, unsigned short* __restrict__ Vsq,
    unsigned short* __restrict__ qh_, unsigned short* __restrict__ ql_,
    unsigned short* __restrict__ kch_)
{
  int h = blockIdx.y;
  int n = blockIdx.x * 4 + threadIdx.x / 96;
  int d = threadIdx.x % 96;
  size_t i80 = ((size_t)h * NTOK + n) * 80 + d;
  size_t i96 = ((size_t)h * NTOK + n) * 96 + d;
  if (d < 80) {
    float v = Ks[i80];
    unsigned short hs = f2bf(v);
    Ksh[i96] = hs; Ksl[i96] = f2bf(v - bf2f(hs));
    float vv = Vs[i80];
    Vsb[i80] = f2bf(vv); Vsq[i80] = f2bf(vv * vv);
  } else {
    Ksh[i96] = 0; Ksl[i96] = 0; qh_[i96] = 0; ql_[i96] = 0; kch_[i96] = 0;
  }
}

// ---------------- per-(h,d) mean / rstd of q over tokens --------------------
__global__ __launch_bounds__(128) void k_qstats(
    const float* __restrict__ qb, float* __restrict__ mu, float* __restrict__ rstd)
{
  const int h = blockIdx.x / DH, d = blockIdx.x % DH;
  const int tid = threadIdx.x;
  float s = 0.f, s2 = 0.f;
  for (int n = tid; n < NTOK; n += 128) {
    float v = qb[((size_t)h * NTOK + n) * 80 + d];
    s += v; s2 = fmaf(v, v, s2);
  }
#pragma unroll
  for (int off = 32; off; off >>= 1) { s += __shfl_xor(s, off, 64); s2 += __shfl_xor(s2, off, 64); }
  __shared__ float sh[4];
  if ((tid & 63) == 0) { sh[(tid >> 6) * 2] = s; sh[(tid >> 6) * 2 + 1] = s2; }
  __syncthreads();
  if (tid == 0) {
    float S = sh[0] + sh[2], S2 = sh[1] + sh[3];
    float mval = S * (1.f / NTOK);
    float var = S2 * (1.f / NTOK) - mval * mval;
    mu[h * DH + d] = mval;
    rstd[h * DH + d] = rsqrtf(var + 1e-5f);
  }
}

// ---------------- pass A (z=4, XCD-swizzled): logits; fp16 S; per-row LSE ---
__global__ __launch_bounds__(256) void k_passA(
    const unsigned short* __restrict__ qh_, const unsigned short* __restrict__ ql_,
    const unsigned short* __restrict__ Ksh, const unsigned short* __restrict__ Ksl,
    const unsigned short* __restrict__ kch_,
    unsigned short* __restrict__ S16, float* __restrict__ mSz, float* __restrict__ lSz,
    float* __restrict__ mCz, float* __restrict__ lCz)
{
  const int bid = blockIdx.x;
  const int swz = (bid & 7) * 128 + (bid >> 3);   // 1024 % 8 == 0: bijective
  const int q0 = (swz & 31) * 64;
  const int h  = (swz >> 5) & 7;
  const int z  = swz >> 8;
  const int tid = threadIdx.x;
  const int w = tid >> 6, l = tid & 63;
  const int c = l & 15, g = l >> 4;

  __shared__ unsigned short sKh[64 * 104];
  __shared__ unsigned short sKl[64 * 104];

  bf16x8 qhf[3], qlf[3];
  {
    const size_t qrow = ((size_t)h * NTOK + q0 + w * 16 + c) * 96;
#pragma unroll
    for (int kc = 0; kc < 3; ++kc) {
      qhf[kc] = *(const bf16x8*)(qh_ + qrow + kc * 32 + g * 8);
      qlf[kc] = *(const bf16x8*)(ql_ + qrow + kc * 32 + g * 8);
    }
  }
  float m[4], lse[4], mc[4], lc[4];
#pragma unroll
  for (int r = 0; r < 4; ++r) { m[r] = -INFINITY; lse[r] = 0.f; mc[r] = -INFINITY; lc[r] = 0.f; }

  // ---- style: 8 key tiles of 64 ----
  for (int t = 0; t < 8; ++t) {
    const size_t kbase = ((size_t)h * NTOK + z * 512 + t * 64) * 96;
    __syncthreads();
    for (int f = tid; f < 768; f += 256) {
      int row = f / 12, ch = f % 12;
      *(bf16x8*)(sKh + row * 104 + ch * 8) = *(const bf16x8*)(Ksh + kbase + row * 96 + ch * 8);
      *(bf16x8*)(sKl + row * 104 + ch * 8) = *(const bf16x8*)(Ksl + kbase + row * 96 + ch * 8);
    }
    __syncthreads();
#pragma unroll
    for (int ct = 0; ct < 4; ++ct) {
      f32x4 D = {0.f, 0.f, 0.f, 0.f};
      const int krow = (ct * 16 + c) * 104 + g * 8;
#pragma unroll
      for (int kc = 0; kc < 3; ++kc) {
        bf16x8 bh = *(const bf16x8*)(sKh + krow + kc * 32);
        D = __builtin_amdgcn_mfma_f32_16x16x32_bf16(qhf[kc], bh, D, 0, 0, 0);
      }
#pragma unroll
      for (int kc = 0; kc < 3; ++kc) {
        bf16x8 bl = *(const bf16x8*)(sKl + krow + kc * 32);
        D = __builtin_amdgcn_mfma_f32_16x16x32_bf16(qhf[kc], bl, D, 0, 0, 0);
      }
#pragma unroll
      for (int kc = 0; kc < 3; ++kc) {
        bf16x8 bh = *(const bf16x8*)(sKh + krow + kc * 32);
        D = __builtin_amdgcn_mfma_f32_16x16x32_bf16(qlf[kc], bh, D, 0, 0, 0);
      }
#pragma unroll
      for (int r = 0; r < 4; ++r) {
        float s = D[r] * TSCALE_F;
        __half hh = __float2half(s);
        S16[((size_t)h * NTOK + q0 + w * 16 + g * 4 + r) * 2048 + z * 512 + t * 64 + ct * 16 + c] =
            __half_as_ushort(hh);
        float mn = fmaxf(m[r], s);
        lse[r] = lse[r] * __expf(m[r] - mn) + __expf(s - mn);
        m[r] = mn;
      }
    }
  }
  // ---- content: 8 key tiles ----
  for (int t = 0; t < 8; ++t) {
    const size_t kbase = ((size_t)h * NTOK + z * 512 + t * 64) * 96;
    __syncthreads();
    for (int f = tid; f < 768; f += 256) {
      int row = f / 12, ch = f % 12;
      *(bf16x8*)(sKh + row * 104 + ch * 8) = *(const bf16x8*)(kch_ + kbase + row * 96 + ch * 8);
    }
    __syncthreads();
#pragma unroll
    for (int ct = 0; ct < 4; ++ct) {
      f32x4 D = {0.f, 0.f, 0.f, 0.f};
      const int krow = (ct * 16 + c) * 104 + g * 8;
#pragma unroll
      for (int kc = 0; kc < 3; ++kc) {
        bf16x8 bh = *(const bf16x8*)(sKh + krow + kc * 32);
        D = __builtin_amdgcn_mfma_f32_16x16x32_bf16(qhf[kc], bh, D, 0, 0, 0);
      }
#pragma unroll
      for (int r = 0; r < 4; ++r) {
        float s = D[r] * SCALE_F;
        float mn = fmaxf(mc[r], s);
        lc[r] = lc[r] * __expf(mc[r] - mn) + __expf(s - mn);
        mc[r] = mn;
      }
    }
  }
  // merge across the 16 col-lanes
#pragma unroll
  for (int off = 1; off < 16; off <<= 1) {
#pragma unroll
    for (int r = 0; r < 4; ++r) {
      float mo = __shfl_xor(m[r], off, 64), lo = __shfl_xor(lse[r], off, 64);
      float mn = fmaxf(m[r], mo);
      lse[r] = lse[r] * __expf(m[r] - mn) + lo * __expf(mo - mn);
      m[r] = mn;
      float mo2 = __shfl_xor(mc[r], off, 64), lo2 = __shfl_xor(lc[r], off, 64);
      float mn2 = fmaxf(mc[r], mo2);
      lc[r] = lc[r] * __expf(mc[r] - mn2) + lo2 * __expf(mo2 - mn2);
      mc[r] = mn2;
    }
  }
  if (c == 0) {
    size_t base = (size_t)(z * 8 + h) * NTOK + q0 + w * 16 + g * 4;
#pragma unroll
    for (int r = 0; r < 4; ++r) {
      mSz[base + r] = m[r]; lSz[base + r] = lse[r];
      mCz[base + r] = mc[r]; lCz[base + r] = lc[r];
    }
  }
}

// ---------------- gate: combine 4 z-slices, lambda, M ------------------------
__global__ __launch_bounds__(256) void k_gate(
    const float* __restrict__ mSz, const float* __restrict__ lSz,
    const float* __restrict__ mCz, const float* __restrict__ lCz,
    float* __restrict__ M_, float* __restrict__ lam_)
{
  int n = blockIdx.x * 256 + threadIdx.x;
  if (n >= NTOK) return;
  float msf[NH], mcf[NH], sum = 0.f;
#pragma unroll
  for (int h = 0; h < NH; ++h) {
    float mm = -INFINITY, cm = -INFINITY;
#pragma unroll
    for (int zz = 0; zz < 4; ++zz) {
      mm = fmaxf(mm, mSz[(size_t)(zz * 8 + h) * NTOK + n]);
      cm = fmaxf(cm, mCz[(size_t)(zz * 8 + h) * NTOK + n]);
    }
    float ls = 0.f, lcs = 0.f;
#pragma unroll
    for (int zz = 0; zz < 4; ++zz) {
      ls  += lSz[(size_t)(zz * 8 + h) * NTOK + n] * __expf(mSz[(size_t)(zz * 8 + h) * NTOK + n] - mm);
      lcs += lCz[(size_t)(zz * 8 + h) * NTOK + n] * __expf(mCz[(size_t)(zz * 8 + h) * NTOK + n] - cm);
    }
    float lse_s = mm + __logf(ls);
    float lse_c = cm + __logf(lcs);
    msf[h] = mm; mcf[h] = cm;
    sum += fminf(fmaxf(lse_s - lse_c, -20.f), 20.f);
  }
  float lam = 1.f + (LMAX_F - 1.f) * (1.f / (1.f + __expf(-sum * (1.f / NH))));
  lam_[n] = lam;
#pragma unroll
  for (int h = 0; h < NH; ++h)
    M_[h * NTOK + n] = fmaxf(lam * msf[h], mcf[h]);
}

// ---------------- top-k threshold: 16-bit ballot bisection on fp16 S --------
__global__ __launch_bounds__(512) void k_topk(const unsigned short* __restrict__ S16,
                                              unsigned* __restrict__ thr_)
{
  const int h = blockIdx.y;
  const int n = blockIdx.x * 8 + (threadIdx.x >> 6);
  const int l = threadIdx.x & 63;
  const unsigned short* Srow = S16 + ((size_t)h * NTOK + n) * 2048;
  unsigned kv[32];
#pragma unroll
  for (int t = 0; t < 4; ++t) {
    uint4 v = ((const uint4*)Srow)[t * 64 + l];
    unsigned dw[4] = {v.x, v.y, v.z, v.w};
#pragma unroll
    for (int i = 0; i < 8; ++i) {
      unsigned u = (dw[i >> 1] >> ((i & 1) * 16)) & 0xFFFFu;
      kv[t * 8 + i] = sk16(u);
    }
  }
  unsigned klo = 0u, khi = 65536u;
  for (int it = 0; it < 16; ++it) {
    unsigned mid = (klo + khi) >> 1;
    int cnt = 0;
#pragma unroll
    for (int t = 0; t < 32; ++t)
      cnt += __popcll(__ballot(kv[t] >= mid));
    if (cnt == TOPKN) { klo = mid; break; }
    if (cnt > TOPKN) klo = mid; else khi = mid;
    if (khi - klo <= 1u) break;
  }
  if (l == 0) thr_[h * NTOK + n] = klo;
}

// ---------------- pass B (z=4, XCD-swizzled): fp16-S read + PV MFMA ---------
__global__ __launch_bounds__(256) void k_passB(
    const unsigned short* __restrict__ qh_, const unsigned short* __restrict__ kch_,
    const unsigned short* __restrict__ Vsb, const unsigned short* __restrict__ Vsq,
    const unsigned short* __restrict__ vcb, const unsigned short* __restrict__ vcq,
    const unsigned short* __restrict__ S16,
    const float* __restrict__ M_, const float* __restrict__ lam_,
    const unsigned* __restrict__ thr_,
    float* __restrict__ oP, float* __restrict__ sP, float* __restrict__ denP)
{
  const int bid = blockIdx.x;
  const int swz = (bid & 7) * 128 + (bid >> 3);
  const int q0 = (swz & 31) * 64;
  const int h  = (swz >> 5) & 7;
  const int z  = swz >> 8;
  const int tid = threadIdx.x;
  const int w = tid >> 6, l = tid & 63;
  const int c = l & 15, g = l >> 4;

  __shared__ char arena[45568];
  unsigned short* S_lds   = (unsigned short*)arena;            // [64][72] fp16 (style)
  unsigned short* kch_lds = (unsigned short*)arena;            // [64][104] (content)
  unsigned short* P_lds   = (unsigned short*)(arena + 13312);  // [4][16][72]
  unsigned short* vT      = (unsigned short*)(arena + 22528);  // [80][72]
  unsigned short* vqT     = (unsigned short*)(arena + 34048);  // [80][72]
  __shared__ float Mr[64], lamr[64], den_l[64];
  __shared__ unsigned thrr[64];

  if (tid < 64) {
    int n = q0 + tid;
    Mr[tid] = M_[h * NTOK + n];
    lamr[tid] = lam_[n];
    thrr[tid] = thr_[h * NTOK + n];
    den_l[tid] = 0.f;
  }
  bf16x8 qhf[3];
  {
    const size_t qrow = ((size_t)h * NTOK + q0 + w * 16 + c) * 96;
#pragma unroll
    for (int kc = 0; kc < 3; ++kc)
      qhf[kc] = *(const bf16x8*)(qh_ + qrow + kc * 32 + g * 8);
  }
  __syncthreads();
  const float myLam = lamr[w * 16 + c], myM = Mr[w * 16 + c];
  const unsigned myThr = thrr[w * 16 + c];
  float myM4[4];
#pragma unroll
  for (int r = 0; r < 4; ++r) myM4[r] = Mr[w * 16 + g * 4 + r];

  f32x4 oacc[5], sacc[5];
#pragma unroll
  for (int dt = 0; dt < 5; ++dt) { oacc[dt] = (f32x4){0.f,0.f,0.f,0.f}; sacc[dt] = (f32x4){0.f,0.f,0.f,0.f}; }
  float denS = 0.f, denC[4] = {0.f, 0.f, 0.f, 0.f};

  // ---- style tiles: P from stored fp16 S ----
  for (int t = 0; t < 8; ++t) {
    const int k0 = z * 512 + t * 64;
    __syncthreads();
    for (int f = tid; f < 512; f += 256) {
      int row = f >> 3, ch = f & 7;
      *(uint4*)&S_lds[row * 72 + ch * 8] =
          *(const uint4*)(S16 + ((size_t)h * NTOK + q0 + row) * 2048 + k0 + ch * 8);
    }
    for (int f = tid; f < 320; f += 256) {
      int kp = f & 31, ch = f >> 5;
      const size_t vb = ((size_t)h * NTOK + k0 + kp * 2) * 80 + ch * 8;
      bf16x8 a = *(const bf16x8*)(Vsb + vb);
      bf16x8 b = *(const bf16x8*)(Vsb + vb + 80);
      bf16x8 aq = *(const bf16x8*)(Vsq + vb);
      bf16x8 bq = *(const bf16x8*)(Vsq + vb + 80);
#pragma unroll
      for (int j = 0; j < 8; ++j) {
        int d = ch * 8 + j;
        *(unsigned*)&vT[d * 72 + kp * 2]  = ((unsigned)(unsigned short)b[j] << 16) | (unsigned short)a[j];
        *(unsigned*)&vqT[d * 72 + kp * 2] = ((unsigned)(unsigned short)bq[j] << 16) | (unsigned short)aq[j];
      }
    }
    __syncthreads();
    bf16x8 pa[2];
#pragma unroll
    for (int kc = 0; kc < 2; ++kc) {
      uint4 sv = *(const uint4*)&S_lds[(w * 16 + c) * 72 + kc * 32 + g * 8];
      unsigned dw[4] = {sv.x, sv.y, sv.z, sv.w};
      bf16x8 pk;
#pragma unroll
      for (int i = 0; i < 8; ++i) {
        unsigned u = (dw[i >> 1] >> ((i & 1) * 16)) & 0xFFFFu;
        float s = __half2float(__ushort_as_half((unsigned short)u));
        float wv = (sk16(u) >= myThr) ? __expf(myLam * s - myM) : 0.f;
        denS += wv;
        pk[i] = (short)f2bf(wv);
      }
      pa[kc] = pk;
    }
#pragma unroll
    for (int dt = 0; dt < 5; ++dt) {
#pragma unroll
      for (int kc = 0; kc < 2; ++kc) {
        bf16x8 bv  = *(const bf16x8*)&vT[(dt * 16 + c) * 72 + kc * 32 + g * 8];
        bf16x8 bvq = *(const bf16x8*)&vqT[(dt * 16 + c) * 72 + kc * 32 + g * 8];
        oacc[dt] = __builtin_amdgcn_mfma_f32_16x16x32_bf16(pa[kc], bv, oacc[dt], 0, 0, 0);
        sacc[dt] = __builtin_amdgcn_mfma_f32_16x16x32_bf16(pa[kc], bvq, sacc[dt], 0, 0, 0);
      }
    }
  }
  // ---- content tiles: recompute logits, P via LDS ----
  for (int t = 0; t < 8; ++t) {
    const int k0 = z * 512 + t * 64;
    __syncthreads();
    for (int f = tid; f < 768; f += 256) {
      int row = f / 12, ch = f % 12;
      *(bf16x8*)(kch_lds + row * 104 + ch * 8) =
          *(const bf16x8*)(kch_ + ((size_t)h * NTOK + k0 + row) * 96 + ch * 8);
    }
    for (int f = tid; f < 320; f += 256) {
      int kp = f & 31, ch = f >> 5;
      const size_t vb = ((size_t)h * NTOK + k0 + kp * 2) * 80 + ch * 8;
      bf16x8 a = *(const bf16x8*)(vcb + vb);
      bf16x8 b = *(const bf16x8*)(vcb + vb + 80);
      bf16x8 aq = *(const bf16x8*)(vcq + vb);
      bf16x8 bq = *(const bf16x8*)(vcq + vb + 80);
#pragma unroll
      for (int j = 0; j < 8; ++j) {
        int d = ch * 8 + j;
        *(unsigned*)&vT[d * 72 + kp * 2]  = ((unsigned)(unsigned short)b[j] << 16) | (unsigned short)a[j];
        *(unsigned*)&vqT[d * 72 + kp * 2] = ((unsigned)(unsigned short)bq[j] << 16) | (unsigned short)aq[j];
      }
    }
    __syncthreads();
#pragma unroll
    for (int ct = 0; ct < 4; ++ct) {
      f32x4 D = {0.f, 0.f, 0.f, 0.f};
      const int krow = (ct * 16 + c) * 104 + g * 8;
#pragma unroll
      for (int kc = 0; kc < 3; ++kc) {
        bf16x8 bh = *(const bf16x8*)(kch_lds + krow + kc * 32);
        D = __builtin_amdgcn_mfma_f32_16x16x32_bf16(qhf[kc], bh, D, 0, 0, 0);
      }
#pragma unroll
      for (int r = 0; r < 4; ++r) {
        float s = D[r] * SCALE_F;
        float wv = __expf(s - myM4[r]);
        denC[r] += wv;
        P_lds[w * 1152 + (g * 4 + r) * 72 + ct * 16 + c] = f2bf(wv);
      }
    }
    __syncthreads();
    bf16x8 pa0 = *(const bf16x8*)(P_lds + w * 1152 + c * 72 + g * 8);
    bf16x8 pa1 = *(const bf16x8*)(P_lds + w * 1152 + c * 72 + 32 + g * 8);
#pragma unroll
    for (int dt = 0; dt < 5; ++dt) {
      bf16x8 bv0  = *(const bf16x8*)&vT[(dt * 16 + c) * 72 + g * 8];
      bf16x8 bvq0 = *(const bf16x8*)&vqT[(dt * 16 + c) * 72 + g * 8];
      bf16x8 bv1  = *(const bf16x8*)&vT[(dt * 16 + c) * 72 + 32 + g * 8];
      bf16x8 bvq1 = *(const bf16x8*)&vqT[(dt * 16 + c) * 72 + 32 + g * 8];
      oacc[dt] = __builtin_amdgcn_mfma_f32_16x16x32_bf16(pa0, bv0, oacc[dt], 0, 0, 0);
      sacc[dt] = __builtin_amdgcn_mfma_f32_16x16x32_bf16(pa0, bvq0, sacc[dt], 0, 0, 0);
      oacc[dt] = __builtin_amdgcn_mfma_f32_16x16x32_bf16(pa1, bv1, oacc[dt], 0, 0, 0);
      sacc[dt] = __builtin_amdgcn_mfma_f32_16x16x32_bf16(pa1, bvq1, sacc[dt], 0, 0, 0);
    }
  }
  // ---- denominators ----
  denS += __shfl_xor(denS, 16, 64);
  denS += __shfl_xor(denS, 32, 64);
#pragma unroll
  for (int off = 1; off < 16; off <<= 1)
#pragma unroll
    for (int r = 0; r < 4; ++r) denC[r] += __shfl_xor(denC[r], off, 64);
  if (l < 16) atomicAdd(&den_l[w * 16 + l], denS);
  if (c == 0) {
#pragma unroll
    for (int r = 0; r < 4; ++r) atomicAdd(&den_l[w * 16 + g * 4 + r], denC[r]);
  }
  __syncthreads();
  const size_t base = (size_t)(z * 8 + h) * NTOK + q0 + w * 16;
#pragma unroll
  for (int dt = 0; dt < 5; ++dt)
#pragma unroll
    for (int r = 0; r < 4; ++r) {
      size_t o = (base + g * 4 + r) * 80 + dt * 16 + c;
      oP[o] = oacc[dt][r];
      sP[o] = sacc[dt][r];
    }
  if (tid < 64) denP[(size_t)(z * 8 + h) * NTOK + q0 + tid] = den_l[tid];
}

// ---------------- finalize: combine 4 z-slices + AdaIN epilogue -------------
__global__ __launch_bounds__(256) void k_fin(
    const float* __restrict__ oP, const float* __restrict__ sP,
    const float* __restrict__ denP, const float* __restrict__ qb,
    const float* __restrict__ mu, const float* __restrict__ rstd,
    const float* __restrict__ gate, float* __restrict__ Ob)
{
  int idx = blockIdx.x * 256 + threadIdx.x;
  int h = idx / (NTOK * 80);
  int rem = idx - h * (NTOK * 80);
  int n = rem / 80, d = rem - n * 80;
  float den = 0.f, o = 0.f, sq = 0.f;
#pragma unroll
  for (int zz = 0; zz < 4; ++zz) {
    den += denP[(size_t)(zz * 8 + h) * NTOK + n];
    size_t p = ((size_t)(zz * 8 + h) * NTOK + n) * 80 + d;
    o += oP[p];
    sq += sP[p];
  }
  o /= den;
  sq /= den;
  float vstd = sqrtf(fmaxf(sq - o * o, 1e-5f));
  float g = tanhf(gate[0]);
  float qn = (qb[((size_t)h * NTOK + n) * 80 + d] - mu[h * DH + d]) * rstd[h * DH + d];
  Ob[(size_t)n * QD + h * DH + d] = fmaf(g * vstd, qn, o);
}

// ---------------- final projection: split-bf16 MFMA, out = Ob@Wo^T + bo -----
__global__ __launch_bounds__(256) void k_finalmm(
    const float* __restrict__ A, const float* __restrict__ W,
    const float* __restrict__ bias, float* __restrict__ out)
{
  const int n0 = blockIdx.y * 64, c0 = blockIdx.x * 64;
  const int tid = threadIdx.x;
  const int w = tid >> 6, l = tid & 63;
  const int cc = l & 15, g = l >> 4;

  __shared__ unsigned short sXh[64 * 72];
  __shared__ unsigned short sXl[64 * 72];
  __shared__ unsigned short sWh[64 * 72];
  __shared__ unsigned short sWl[64 * 72];

  f32x4 D[4];
#pragma unroll
  for (int ct = 0; ct < 4; ++ct) D[ct] = (f32x4){0.f, 0.f, 0.f, 0.f};

  for (int k0 = 0; k0 < QD; k0 += 64) {
    __syncthreads();
#pragma unroll
    for (int it = 0; it < 4; ++it) {
      int f = tid + it * 256;
      int row = f >> 4, col4 = f & 15;
      float4 xa = *(const float4*)(A + (size_t)(n0 + row) * QD + k0 + col4 * 4);
      float4 wa = *(const float4*)(W + (size_t)(c0 + row) * QD + k0 + col4 * 4);
      u16x4 xh, xl, wh, wl;
      float xv[4] = {xa.x, xa.y, xa.z, xa.w};
      float wv[4] = {wa.x, wa.y, wa.z, wa.w};
#pragma unroll
      for (int j = 0; j < 4; ++j) {
        unsigned short h1 = f2bf(xv[j]);
        xh[j] = h1; xl[j] = f2bf(xv[j] - bf2f(h1));
        unsigned short h2 = f2bf(wv[j]);
        wh[j] = h2; wl[j] = f2bf(wv[j] - bf2f(h2));
      }
      *(u16x4*)&sXh[row * 72 + col4 * 4] = xh;
      *(u16x4*)&sXl[row * 72 + col4 * 4] = xl;
      *(u16x4*)&sWh[row * 72 + col4 * 4] = wh;
      *(u16x4*)&sWl[row * 72 + col4 * 4] = wl;
    }
    __syncthreads();
    bf16x8 ah[2], al[2];
#pragma unroll
    for (int kc = 0; kc < 2; ++kc) {
      ah[kc] = *(const bf16x8*)&sXh[(w * 16 + cc) * 72 + kc * 32 + g * 8];
      al[kc] = *(const bf16x8*)&sXl[(w * 16 + cc) * 72 + kc * 32 + g * 8];
    }
#pragma unroll
    for (int ct = 0; ct < 4; ++ct) {
#pragma unroll
      for (int kc = 0; kc < 2; ++kc) {
        bf16x8 bh = *(const bf16x8*)&sWh[(ct * 16 + cc) * 72 + kc * 32 + g * 8];
        bf16x8 bl = *(const bf16x8*)&sWl[(ct * 16 + cc) * 72 + kc * 32 + g * 8];
        D[ct] = __builtin_amdgcn_mfma_f32_16x16x32_bf16(ah[kc], bh, D[ct], 0, 0, 0);
        D[ct] = __builtin_amdgcn_mfma_f32_16x16x32_bf16(ah[kc], bl, D[ct], 0, 0, 0);
        D[ct] = __builtin_amdgcn_mfma_f32_16x16x32_bf16(al[kc], bh, D[ct], 0, 0, 0);
      }
    }
  }
#pragma unroll
  for (int ct = 0; ct < 4; ++ct) {
#pragma unroll
    for (int r = 0; r < 4; ++r) {
      int n = n0 + w * 16 + g * 4 + r;
      int ccol = c0 + ct * 16 + cc;
      out[(size_t)n * QD + ccol] = D[ct][r] + bias[ccol];
    }
  }
}

extern "C" void kernel_launch(void* const* d_in, const int* in_sizes, int n_in,
                              void* d_out, int out_size, void* d_ws, size_t ws_size,
                              hipStream_t stream) {
  const float* x    = (const float*)d_in[0];
  const float* Qc   = (const float*)d_in[1];
  const float* Ks   = (const float*)d_in[2];
  const float* Vs   = (const float*)d_in[3];
  const float* Wq   = (const float*)d_in[4];
  const float* Wk   = (const float*)d_in[5];
  const float* Wv   = (const float*)d_in[6];
  const float* Wo   = (const float*)d_in[7];
  const float* bo   = (const float*)d_in[8];
  const float* gate = (const float*)d_in[9];
  float* out = (float*)d_out;
  float* w = (float*)d_ws;

  float* qb   = w + OFF_QB;
  float* Ob   = w + OFF_OB;
  unsigned short* qh_  = (unsigned short*)(w + OFF_QH);
  unsigned short* ql_  = (unsigned short*)(w + OFF_QL);
  unsigned short* kch_ = (unsigned short*)(w + OFF_KCH);
  unsigned short* Ksh  = (unsigned short*)(w + OFF_KSH);
  unsigned short* Ksl  = (unsigned short*)(w + OFF_KSL);
  unsigned short* vcb  = (unsigned short*)(w + OFF_VCB);
  unsigned short* vcq  = (unsigned short*)(w + OFF_VCQ);
  unsigned short* Vsb  = (unsigned short*)(w + OFF_VSB);
  unsigned short* Vsq  = (unsigned short*)(w + OFF_VSQ);
  float* oP   = w + OFF_OP;
  float* sP   = w + OFF_SP;
  float* denP = w + OFF_DEN;
  float* mSz  = w + OFF_MSZ;
  float* lSz  = w + OFF_LSZ;
  float* mCz  = w + OFF_MCZ;
  float* lCz  = w + OFF_LCZ;
  float* M_   = w + OFF_M;
  float* lam_ = w + OFF_LAM;
  unsigned* thr_ = (unsigned*)(w + OFF_THR);
  float* mu   = w + OFF_MU;
  float* rstd = w + OFF_RSTD;
  unsigned short* S16 = (unsigned short*)(w + OFF_S16);

  k_projmm<<<dim3(10, 32, 3), 256, 0, stream>>>(x, Wq, Wk, Wv, Qc, qb, qh_, ql_, kch_, vcb, vcq);
  k_cvt<<<dim3(512, 8), 384, 0, stream>>>(Ks, Vs, Ksh, Ksl, Vsb, Vsq, qh_, ql_, kch_);
  k_qstats<<<dim3(640), 128, 0, stream>>>(qb, mu, rstd);
  k_passA<<<dim3(1024), 256, 0, stream>>>(qh_, ql_, Ksh, Ksl, kch_, S16, mSz, lSz, mCz, lCz);
  k_gate<<<dim3(8), 256, 0, stream>>>(mSz, lSz, mCz, lCz, M_, lam_);
  k_topk<<<dim3(256, 8), 512, 0, stream>>>(S16, thr_);
  k_passB<<<dim3(1024), 256, 0, stream>>>(qh_, kch_, Vsb, Vsq, vcb, vcq, S16, M_, lam_, thr_, oP, sP, denP);
  k_fin<<<dim3(5120), 256, 0, stream>>>(oP, sP, denP, qb, mu, rstd, gate, Ob);
  k_finalmm<<<dim3(10, 32), 256, 0, stream>>>(Ob, Wo, bo, out);
}